// Round 15
// baseline (393.334 us; speedup 1.0000x reference)
//
#include <hip/hip_runtime.h>

#define NS 1024   // spins / steps
#define NB 4096   // batch
#define NH 128    // hidden
#define HLF 512   // magnetization threshold
#define NT 512    // 8 waves, one 16-batch chain per CU

typedef __attribute__((ext_vector_type(8))) short short8;
typedef __attribute__((ext_vector_type(4))) float f32x4;

__device__ __forceinline__ short f2bf(float x) {   // fp32 -> bf16 RNE
    unsigned u = __builtin_bit_cast(unsigned, x);
    u = (u + 0x7FFFu + ((u >> 16) & 1u)) >> 16;
    return (short)u;
}
__device__ __forceinline__ float vexp2(float x) {  // raw v_exp_f32 (2^x)
    float r;
    asm("v_exp_f32 %0, %1" : "=v"(r) : "v"(x));
    return r;
}

// LDS-only barrier: drain lgkm, NOT vmcnt — spin prefetch and out stores stay
// in flight across steps.
#define BARRIER() asm volatile("s_waitcnt lgkmcnt(0)\n\ts_barrier" ::: "memory")
#define MFMA __builtin_amdgcn_mfma_f32_16x16x32_bf16

// R14 structure (382us) + straggler split across SIMDs:
//  wave 1 (SIMD1): logit MFMAs for out[T-1] -> lp[T&1] (64B LDS)
//  wave 2 (SIMD2): softmax+mask+store of out[T-2] from lp[(T-1)&1]
// All other waves run the bare recurrence. Masks: uniform 2-deep shift reg.
__global__ __launch_bounds__(NT, 1)
void pwf_kernel(const float* __restrict__ data_in,
                const float* __restrict__ W_ih,
                const float* __restrict__ W_hh,
                const float* __restrict__ b_ih,
                const float* __restrict__ b_hh,
                const float* __restrict__ W_lin,
                const float* __restrict__ b_lin,
                float* __restrict__ out)
{
    // rotated layout: elem(batch b, hid) at b*128 + ((hid + 8*b) & 127) [shorts]
    __shared__ __align__(16) short hlds[2][16 * NH];   // 8 KB, double-buffered
    __shared__ float lp[2][16];                        // logit-diff handoff

    const int tid = threadIdx.x;
    const int w   = tid >> 6;       // wave 0..7 (hidden slice 16w..16w+15)
    const int l   = tid & 63;
    const int g   = l >> 4;         // k-group 0..3
    const int b   = l & 15;         // batch col / A-row m
    const int b0  = blockIdx.x * 16;
    const int bb  = b0 + b;         // this lane's tracked batch row

    const float TL2E = 2.8853900817779268f;  // 2*log2(e)
    const float L2E  = 1.4426950408889634f;  // log2(e)

    // ---- A fragments: W_hh rows (exp2-domain), registers forever ----
    const int hrow = w * 16 + b;
    short8 af0, af1, af2, af3;
    {
        short8 t[4];
        #pragma unroll
        for (int kb = 0; kb < 4; ++kb) {
            const float* src = W_hh + hrow * NH + kb * 32 + g * 8;
            short8 v;
            #pragma unroll
            for (int i = 0; i < 8; ++i) v[i] = f2bf(TL2E * src[i]);
            t[kb] = v;
        }
        af0 = t[0]; af1 = t[1]; af2 = t[2]; af3 = t[3];
    }
    // ---- logit A-fragments (wave 1 uses): row 0 = L2E*(Wlin[1]-Wlin[0]) ----
    short8 lf0, lf1, lf2, lf3;
    {
        short8 t[4];
        #pragma unroll
        for (int kb = 0; kb < 4; ++kb) {
            short8 v;
            #pragma unroll
            for (int i = 0; i < 8; ++i) {
                const int k = kb * 32 + g * 8 + i;
                v[i] = (b == 0) ? f2bf(L2E * (W_lin[NH + k] - W_lin[k])) : (short)0;
            }
            t[kb] = v;
        }
        lf0 = t[0]; lf1 = t[1]; lf2 = t[2]; lf3 = t[3];
    }
    // ---- per-C-reg input contributions: hid = w*16 + 4g + r ----
    float cv0[4], cv1[4];
    #pragma unroll
    for (int r = 0; r < 4; ++r) {
        const int hid = w * 16 + 4 * g + r;
        const float cb = b_ih[hid] + b_hh[hid];
        cv0[r] = TL2E * (W_ih[hid * 2 + 0] + cb);
        cv1[r] = TL2E * (W_ih[hid * 2 + 1] + cb);
    }
    const float blD = L2E * (b_lin[1] - b_lin[0]);

    // ---- LDS offsets (shorts) ----
    int aoff[4];
    #pragma unroll
    for (int kb = 0; kb < 4; ++kb)
        aoff[kb] = b * NH + ((kb * 32 + g * 8 + 8 * b) & 127);
    const int woffs = b * NH + ((w * 16 + 4 * g + 8 * b) & 127);

    // ---- init ----
    ((uint4*)hlds)[tid] = make_uint4(0u, 0u, 0u, 0u);   // 512*16B = both buffers
    int   cntup = 0, cntdn = 0, sel = 0;   // per-lane spin tracking (batch bb)
    int   e1u = 0, e1d = 0;                // snap at T-1: spins 0..T-2
    int   e2u = 0, e2d = 0;                // snap at T-2: spins 0..T-3
    float s0 = data_in[((size_t)0 * NB + bb) * 2];
    float s1 = data_in[((size_t)1 * NB + bb) * 2];
    BARRIER();

#define STEP(T, P, SU)                                                         \
    {                                                                          \
        const short* hr = hlds[P];                                             \
        short* hw = hlds[(P) ^ 1];                                             \
        /* C-init with input contribution (sel = spin T-1, set last step) */   \
        f32x4 cini;                                                            \
        _Pragma("unroll")                                                      \
        for (int r = 0; r < 4; ++r) cini[r] = sel ? cv1[r] : cv0[r];           \
        const short8 h0 = *(const short8*)&hr[aoff[0]];                        \
        const short8 h1 = *(const short8*)&hr[aoff[1]];                        \
        const short8 h2 = *(const short8*)&hr[aoff[2]];                        \
        const short8 h3 = *(const short8*)&hr[aoff[3]];                        \
        if (w == 2 && (T) >= 2 && l < 16) {  /* epilogue: out[T-2] from lp */  \
            const float ed = lp[((T) - 1) & 1][l];                             \
            float p0 = __builtin_amdgcn_rcpf(1.0f + vexp2(ed));                \
            float p1 = 1.0f - p0;                                              \
            if (e2u) { p0 = 0.0f; p1 = 1.0f; }                                 \
            if (e2d) { p0 = 1.0f; p1 = 0.0f; }   /* down overrides up */       \
            *(float2*)&out[((size_t)((T) - 2) * NB + b0 + l) * 2] =            \
                make_float2(p0, p1);                                           \
        }                                                                      \
        if (w == 1 && (T) >= 1) {   /* logit-diff for out[T-1] -> lp[T&1] */   \
            f32x4 li = {blD, blD, blD, blD};                                   \
            f32x4 zl = {0.f, 0.f, 0.f, 0.f};                                   \
            f32x4 cl01 = MFMA(lf0, h0, li, 0, 0, 0);                           \
            cl01 = MFMA(lf1, h1, cl01, 0, 0, 0);                               \
            f32x4 cl23 = MFMA(lf2, h2, zl, 0, 0, 0);                           \
            cl23 = MFMA(lf3, h3, cl23, 0, 0, 0);                               \
            if (l < 16) lp[(T) & 1][l] = cl01[0] + cl23[0];                    \
        }                                                                      \
        /* mask shift register (uniform, all waves) */                         \
        e2u = e1u; e2d = e1d;                                                  \
        e1u = (cntup >= HLF); e1d = (cntdn >= HLF);   /* spins 0..T-1 */       \
        /* recurrence: two independent 2-deep MFMA chains, cv pre-folded */    \
        f32x4 zz = {0.f, 0.f, 0.f, 0.f};                                       \
        f32x4 c01 = MFMA(af0, h0, cini, 0, 0, 0);                              \
        c01 = MFMA(af1, h1, c01, 0, 0, 0);                                     \
        f32x4 c23 = MFMA(af2, h2, zz, 0, 0, 0);                                \
        c23 = MFMA(af3, h3, c23, 0, 0, 0);                                     \
        float hn[4];                                                           \
        _Pragma("unroll")                                                      \
        for (int r = 0; r < 4; ++r) {                                          \
            const float e = vexp2(c01[r] + c23[r]);                            \
            hn[r] = fmaf(__builtin_amdgcn_rcpf(e + 1.0f), -2.0f, 1.0f);        \
        }                                                                      \
        unsigned pk01, pk23;                                                   \
        asm("v_cvt_pk_bf16_f32 %0, %1, %2" : "=v"(pk01) : "v"(hn[0]), "v"(hn[1])); \
        asm("v_cvt_pk_bf16_f32 %0, %1, %2" : "=v"(pk23) : "v"(hn[2]), "v"(hn[3])); \
        *(uint2*)&hw[woffs] = make_uint2(pk01, pk23);   /* one ds_write_b64 */ \
        {   /* consume spin T, prefetch spin T+2 (per-lane, batch bb) */       \
            const int isup = ((SU) > 0.5f) ? 1 : 0;                            \
            cntup += isup; cntdn += 1 - isup; sel = 1 - isup;                  \
            const int tn = ((T) + 2 < NS) ? (T) + 2 : NS - 1;                  \
            (SU) = data_in[((size_t)tn * NB + bb) * 2];                        \
        }                                                                      \
        BARRIER();                                                             \
    }

    for (int t = 0; t < NS; t += 2) {
        STEP(t, 0, s0)
        STEP(t + 1, 1, s1)
    }

    // ---- post-loop ----
    // wave 2: out[NS-2] from lp[(NS-1)&1] (written at step NS-1), masks = e2
    if (w == 2 && l < 16) {
        const float ed = lp[(NS - 1) & 1][l];
        float p0 = __builtin_amdgcn_rcpf(1.0f + vexp2(ed));
        float p1 = 1.0f - p0;
        if (e2u) { p0 = 0.0f; p1 = 1.0f; }
        if (e2d) { p0 = 1.0f; p1 = 0.0f; }
        *(float2*)&out[((size_t)(NS - 2) * NB + b0 + l) * 2] = make_float2(p0, p1);
    }
    // wave 1: out[NS-1] from h_NS (in hlds[0]), masks = e1 (spins 0..NS-2)
    if (w == 1) {
        const short* hr = hlds[0];
        const short8 h0 = *(const short8*)&hr[aoff[0]];
        const short8 h1 = *(const short8*)&hr[aoff[1]];
        const short8 h2 = *(const short8*)&hr[aoff[2]];
        const short8 h3 = *(const short8*)&hr[aoff[3]];
        f32x4 li = {blD, blD, blD, blD};
        f32x4 zl = {0.f, 0.f, 0.f, 0.f};
        f32x4 cl01 = MFMA(lf0, h0, li, 0, 0, 0);
        cl01 = MFMA(lf1, h1, cl01, 0, 0, 0);
        f32x4 cl23 = MFMA(lf2, h2, zl, 0, 0, 0);
        cl23 = MFMA(lf3, h3, cl23, 0, 0, 0);
        const float fd = cl01[0] + cl23[0];
        if (l < 16) {
            float p0 = __builtin_amdgcn_rcpf(1.0f + vexp2(fd));
            float p1 = 1.0f - p0;
            if (e1u) { p0 = 0.0f; p1 = 1.0f; }
            if (e1d) { p0 = 1.0f; p1 = 0.0f; }
            *(float2*)&out[((size_t)(NS - 1) * NB + b0 + l) * 2] = make_float2(p0, p1);
        }
    }
}

extern "C" void kernel_launch(void* const* d_in, const int* in_sizes, int n_in,
                              void* d_out, int out_size, void* d_ws, size_t ws_size,
                              hipStream_t stream) {
    const float* data_in = (const float*)d_in[0];
    const float* W_ih    = (const float*)d_in[1];
    const float* W_hh    = (const float*)d_in[2];
    const float* b_ih    = (const float*)d_in[3];
    const float* b_hh    = (const float*)d_in[4];
    const float* W_lin   = (const float*)d_in[5];
    const float* b_lin   = (const float*)d_in[6];
    float* out = (float*)d_out;

    dim3 grid(NB / 16);   // 256 blocks, one 16-batch chain per CU
    dim3 block(NT);       // 8 waves (2 per SIMD)
    pwf_kernel<<<grid, block, 0, stream>>>(data_in, W_ih, W_hh, b_ih, b_hh,
                                           W_lin, b_lin, out);
}

// Round 16
// 381.313 us; speedup vs baseline: 1.0315x; 1.0315x over previous
//
#include <hip/hip_runtime.h>

#define NS 1024   // spins / steps
#define NB 4096   // batch
#define NH 128    // hidden
#define HLF 512   // magnetization threshold
#define NT 512    // 8 waves, one 16-batch chain per CU

typedef __attribute__((ext_vector_type(8))) short short8;
typedef __attribute__((ext_vector_type(4))) float f32x4;

__device__ __forceinline__ short f2bf(float x) {   // fp32 -> bf16 RNE
    unsigned u = __builtin_bit_cast(unsigned, x);
    u = (u + 0x7FFFu + ((u >> 16) & 1u)) >> 16;
    return (short)u;
}
__device__ __forceinline__ float vexp2(float x) {  // raw v_exp_f32 (2^x)
    float r;
    asm("v_exp_f32 %0, %1" : "=v"(r) : "v"(x));
    return r;
}

// LDS-only barrier: drain lgkm (h writes), NOT vmcnt — spin prefetch and out
// stores stay in flight across steps.
#define BARRIER() asm volatile("s_waitcnt lgkmcnt(0)\n\ts_barrier" ::: "memory")
#define MFMA __builtin_amdgcn_mfma_f32_16x16x32_bf16

// Converged structure (R14, 382us measured):
//  - transposed compute: D = W_hh·h^T; A = W_hh rows in regs forever;
//    C: lane=batch, regs=4 consecutive hidden -> one contiguous b64 h-write
//  - cv folded into MFMA C-init (tail = exp2 -> rcp -> fma -> cvt_pk)
//  - blD folded into logit C-init; wave 0 carries logits + deferred epilogue
//  - per-lane spin/mask tracking (no ballots, no control LDS)
//  - LDS: bf16 h, rotated: elem(b, hid) at b*128 + ((hid + 8*b) & 127)
//  - lgkm-only barrier, depth-2 spin prefetch
__global__ __launch_bounds__(NT, 1)
void pwf_kernel(const float* __restrict__ data_in,
                const float* __restrict__ W_ih,
                const float* __restrict__ W_hh,
                const float* __restrict__ b_ih,
                const float* __restrict__ b_hh,
                const float* __restrict__ W_lin,
                const float* __restrict__ b_lin,
                float* __restrict__ out)
{
    __shared__ __align__(16) short hlds[2][16 * NH];   // 8 KB, double-buffered

    const int tid = threadIdx.x;
    const int w   = tid >> 6;       // wave 0..7 (hidden slice 16w..16w+15)
    const int l   = tid & 63;
    const int g   = l >> 4;         // k-group 0..3
    const int b   = l & 15;         // batch col / A-row m
    const int b0  = blockIdx.x * 16;
    const int bb  = b0 + b;         // this lane's tracked batch row

    const float TL2E = 2.8853900817779268f;  // 2*log2(e)
    const float L2E  = 1.4426950408889634f;  // log2(e)

    // ---- A fragments: W_hh rows (exp2-domain), registers forever ----
    const int hrow = w * 16 + b;
    short8 af0, af1, af2, af3;
    {
        short8 t[4];
        #pragma unroll
        for (int kb = 0; kb < 4; ++kb) {
            const float* src = W_hh + hrow * NH + kb * 32 + g * 8;
            short8 v;
            #pragma unroll
            for (int i = 0; i < 8; ++i) v[i] = f2bf(TL2E * src[i]);
            t[kb] = v;
        }
        af0 = t[0]; af1 = t[1]; af2 = t[2]; af3 = t[3];
    }
    // ---- logit A-fragments (wave 0): row 0 = L2E*(W_lin[1]-W_lin[0]) ----
    short8 lf0, lf1, lf2, lf3;
    {
        short8 t[4];
        #pragma unroll
        for (int kb = 0; kb < 4; ++kb) {
            short8 v;
            #pragma unroll
            for (int i = 0; i < 8; ++i) {
                const int k = kb * 32 + g * 8 + i;
                v[i] = (b == 0) ? f2bf(L2E * (W_lin[NH + k] - W_lin[k])) : (short)0;
            }
            t[kb] = v;
        }
        lf0 = t[0]; lf1 = t[1]; lf2 = t[2]; lf3 = t[3];
    }
    // ---- per-C-reg input contributions: hid = w*16 + 4g + r ----
    float cv0[4], cv1[4];
    #pragma unroll
    for (int r = 0; r < 4; ++r) {
        const int hid = w * 16 + 4 * g + r;
        const float cb = b_ih[hid] + b_hh[hid];
        cv0[r] = TL2E * (W_ih[hid * 2 + 0] + cb);
        cv1[r] = TL2E * (W_ih[hid * 2 + 1] + cb);
    }
    const float blD = L2E * (b_lin[1] - b_lin[0]);

    // ---- LDS offsets (shorts) ----
    int aoff[4];
    #pragma unroll
    for (int kb = 0; kb < 4; ++kb)
        aoff[kb] = b * NH + ((kb * 32 + g * 8 + 8 * b) & 127);
    const int woffs = b * NH + ((w * 16 + 4 * g + 8 * b) & 127);

    // ---- init ----
    ((uint4*)hlds)[tid] = make_uint4(0u, 0u, 0u, 0u);   // 512*16B = both buffers
    int   cntup = 0, cntdn = 0, sel = 0;   // per-lane spin tracking (batch bb)
    int   e1u = 0, e1d = 0;                // mask snap: spins 0..T-1 (for out[T])
    int   eum = 0, edm = 0;                // masks latched with pending ediff
    float ediff = 0.0f;                    // pending logit-diff (out[T-2])
    float s0 = data_in[((size_t)0 * NB + bb) * 2];
    float s1 = data_in[((size_t)1 * NB + bb) * 2];
    BARRIER();

#define STEP(T, P, SU)                                                         \
    {                                                                          \
        const short* hr = hlds[P];                                             \
        short* hw = hlds[(P) ^ 1];                                             \
        /* C-init with input contribution (sel = spin T-1, set last step) */   \
        f32x4 cini;                                                            \
        _Pragma("unroll")                                                      \
        for (int r = 0; r < 4; ++r) cini[r] = sel ? cv1[r] : cv0[r];           \
        const short8 h0 = *(const short8*)&hr[aoff[0]];                        \
        const short8 h1 = *(const short8*)&hr[aoff[1]];                        \
        const short8 h2 = *(const short8*)&hr[aoff[2]];                        \
        const short8 h3 = *(const short8*)&hr[aoff[3]];                        \
        if (w == 0) {                                                          \
            if ((T) >= 2 && l < 16) {   /* deferred store out[T-2] */          \
                float p0 = __builtin_amdgcn_rcpf(1.0f + vexp2(ediff));         \
                float p1 = 1.0f - p0;                                          \
                if (eum) { p0 = 0.0f; p1 = 1.0f; }                             \
                if (edm) { p0 = 1.0f; p1 = 0.0f; }   /* down overrides */      \
                *(float2*)&out[((size_t)((T) - 2) * NB + b0 + l) * 2] =        \
                    make_float2(p0, p1);                                       \
            }                                                                  \
            if ((T) >= 1) {   /* logit-diff for out[T-1] from h_T frags */     \
                f32x4 li = {blD, blD, blD, blD};                               \
                f32x4 zl = {0.f, 0.f, 0.f, 0.f};                               \
                f32x4 cl01 = MFMA(lf0, h0, li, 0, 0, 0);                       \
                cl01 = MFMA(lf1, h1, cl01, 0, 0, 0);                           \
                f32x4 cl23 = MFMA(lf2, h2, zl, 0, 0, 0);                       \
                cl23 = MFMA(lf3, h3, cl23, 0, 0, 0);                           \
                ediff = cl01[0] + cl23[0];   /* valid on lanes l<16 */         \
                eum = e1u; edm = e1d;        /* masks: spins 0..T-2 */         \
            }                                                                  \
        }                                                                      \
        e1u = (cntup >= HLF);   /* snap spins 0..T-1 (pre-consume) */          \
        e1d = (cntdn >= HLF);                                                  \
        /* recurrence: two independent 2-deep MFMA chains, cv pre-folded */    \
        f32x4 zz = {0.f, 0.f, 0.f, 0.f};                                       \
        f32x4 c01 = MFMA(af0, h0, cini, 0, 0, 0);                              \
        c01 = MFMA(af1, h1, c01, 0, 0, 0);                                     \
        f32x4 c23 = MFMA(af2, h2, zz, 0, 0, 0);                                \
        c23 = MFMA(af3, h3, c23, 0, 0, 0);                                     \
        float hn[4];                                                           \
        _Pragma("unroll")                                                      \
        for (int r = 0; r < 4; ++r) {                                          \
            const float e = vexp2(c01[r] + c23[r]);                            \
            hn[r] = fmaf(__builtin_amdgcn_rcpf(e + 1.0f), -2.0f, 1.0f);        \
        }                                                                      \
        unsigned pk01, pk23;                                                   \
        asm("v_cvt_pk_bf16_f32 %0, %1, %2" : "=v"(pk01) : "v"(hn[0]), "v"(hn[1])); \
        asm("v_cvt_pk_bf16_f32 %0, %1, %2" : "=v"(pk23) : "v"(hn[2]), "v"(hn[3])); \
        *(uint2*)&hw[woffs] = make_uint2(pk01, pk23);   /* one ds_write_b64 */ \
        {   /* consume spin T, prefetch spin T+2 (per-lane, batch bb) */       \
            const int isup = ((SU) > 0.5f) ? 1 : 0;                            \
            cntup += isup; cntdn += 1 - isup; sel = 1 - isup;                  \
            const int tn = ((T) + 2 < NS) ? (T) + 2 : NS - 1;                  \
            (SU) = data_in[((size_t)tn * NB + bb) * 2];                        \
        }                                                                      \
        BARRIER();                                                             \
    }

    for (int t = 0; t < NS; t += 2) {
        STEP(t, 0, s0)
        STEP(t + 1, 1, s1)
    }

    // ---- post-loop: flush out[NS-2]; out[NS-1] from h_NS (in hlds[0]) ----
    if (w == 0) {
        if (l < 16) {   // out[NS-2]: ediff/eum latched at iter NS-1
            float p0 = __builtin_amdgcn_rcpf(1.0f + vexp2(ediff));
            float p1 = 1.0f - p0;
            if (eum) { p0 = 0.0f; p1 = 1.0f; }
            if (edm) { p0 = 1.0f; p1 = 0.0f; }
            *(float2*)&out[((size_t)(NS - 2) * NB + b0 + l) * 2] =
                make_float2(p0, p1);
        }
        const short* hr = hlds[0];
        const short8 h0 = *(const short8*)&hr[aoff[0]];
        const short8 h1 = *(const short8*)&hr[aoff[1]];
        const short8 h2 = *(const short8*)&hr[aoff[2]];
        const short8 h3 = *(const short8*)&hr[aoff[3]];
        f32x4 li = {blD, blD, blD, blD};
        f32x4 zl = {0.f, 0.f, 0.f, 0.f};
        f32x4 cl01 = MFMA(lf0, h0, li, 0, 0, 0);
        cl01 = MFMA(lf1, h1, cl01, 0, 0, 0);
        f32x4 cl23 = MFMA(lf2, h2, zl, 0, 0, 0);
        cl23 = MFMA(lf3, h3, cl23, 0, 0, 0);
        const float fd = cl01[0] + cl23[0];
        if (l < 16) {   // out[NS-1]: masks = e1 = spins 0..NS-2
            float p0 = __builtin_amdgcn_rcpf(1.0f + vexp2(fd));
            float p1 = 1.0f - p0;
            if (e1u) { p0 = 0.0f; p1 = 1.0f; }
            if (e1d) { p0 = 1.0f; p1 = 0.0f; }
            *(float2*)&out[((size_t)(NS - 1) * NB + b0 + l) * 2] =
                make_float2(p0, p1);
        }
    }
}

extern "C" void kernel_launch(void* const* d_in, const int* in_sizes, int n_in,
                              void* d_out, int out_size, void* d_ws, size_t ws_size,
                              hipStream_t stream) {
    const float* data_in = (const float*)d_in[0];
    const float* W_ih    = (const float*)d_in[1];
    const float* W_hh    = (const float*)d_in[2];
    const float* b_ih    = (const float*)d_in[3];
    const float* b_hh    = (const float*)d_in[4];
    const float* W_lin   = (const float*)d_in[5];
    const float* b_lin   = (const float*)d_in[6];
    float* out = (float*)d_out;

    dim3 grid(NB / 16);   // 256 blocks, one 16-batch chain per CU
    dim3 block(NT);       // 8 waves (2 per SIMD)
    pwf_kernel<<<grid, block, 0, stream>>>(data_in, W_ih, W_hh, b_ih, b_hh,
                                           W_lin, b_lin, out);
}